// Round 18
// baseline (475.463 us; speedup 1.0000x reference)
//
#include <hip/hip_runtime.h>
#include <hip/hip_bf16.h>

typedef __attribute__((ext_vector_type(4))) float f32x4;
typedef __attribute__((ext_vector_type(8))) short bf16x8;

__device__ __forceinline__ unsigned short f2bf(float f) {
  union { float f; unsigned int u; } v; v.f = f;
  unsigned int u = v.u;
  unsigned int r = (u + 0x7FFFu + ((u >> 16) & 1u)) >> 16;  // RNE
  return (unsigned short)r;
}

// ---------------- prep: pack W1(rows 4..260) and W2 into MFMA-B fragment order ----
__global__ void pack_w_kernel(const float* __restrict__ W1, const float* __restrict__ W2,
                              unsigned short* __restrict__ Bp1, unsigned short* __restrict__ Bp2) {
  int p = blockIdx.x * 256 + threadIdx.x;
  if (p < 32768) {                      // 256x128 for layer 1 (W1 rows 4..260)
    int j = p & 7, n = (p >> 3) & 127, kb = p >> 10;
    Bp1[p] = f2bf(W1[(4 + kb * 8 + j) * 128 + n]);
  } else if (p < 49152) {               // 128x128 for layer 2
    int q = p - 32768;
    int j = q & 7, n = (q >> 3) & 127, kb = q >> 10;
    Bp2[q] = f2bf(W2[(kb * 8 + j) * 128 + n]);
  }
}

// ---------------- prep: x fp32 -> bf16 ----------------
__global__ void convert_x_kernel(const float* __restrict__ x, unsigned short* __restrict__ xb, int n8) {
  int i = blockIdx.x * blockDim.x + threadIdx.x;
  if (i >= n8) return;
  const float4* s = (const float4*)x + (size_t)i * 2;
  float4 a = s[0], b = s[1];
  unsigned short h[8] = {f2bf(a.x), f2bf(a.y), f2bf(a.z), f2bf(a.w),
                         f2bf(b.x), f2bf(b.y), f2bf(b.z), f2bf(b.w)};
  int4 pk; __builtin_memcpy(&pk, h, 16);
  ((int4*)xb)[i] = pk;
}

constexpr int BM = 64;

// ---------------- main kernel: TWO adjacent tiles per block, reg-staged pipeline ----
// Clean basin (R1-R17 record): 3 blocks/CU, normal-load gather, NT full-line
// epilogue. 4/CU amplifies regardless of store/gather mode (R5/R6/R14/R17).
// Pipeline: tile1 idx/ea issue after TOP0; tile1 gather loads (VGPR, T14-style)
// issue after BAR2 and their HBM latency hides under tile0's H-write + layer-2 +
// O-stage + NT epilogue. bf1r is reloaded per tile (L2-hit, hidden) to keep peak
// VGPR < 170. O-stage is a swizzled 32 KB overlay of Alds (byte ^ (r&7)<<4 --
// consistent for 16B-group-aligned access since XOR touches bits 4-6 only) so
// LDS = 50 KB keeps 3/CU. Mid-loop barriers are lgkmcnt(0)-only (NT stores drain
// in background; R3/R7-validated discipline).
__global__ __launch_bounds__(256, 3)
void edge_nt_x2(const unsigned short* __restrict__ xb,
                const float* __restrict__ ea, const int* __restrict__ eidx,
                const float* __restrict__ W1, const float* __restrict__ b1,
                const float* __restrict__ b2,
                const unsigned short* __restrict__ Bp1, const unsigned short* __restrict__ Bp2,
                float* __restrict__ outp, int E, int ntiles) {
  __shared__ int4 AldsV[2048];     // 32 KB: A-tile [64][256] bf16 swizzled; O-stage overlays (swizzled [64][128] f32)
  __shared__ int4 HldsV[1024];     // 16 KB: h [64][128] bf16 swizzled
  __shared__ float ealds[2][256];  // 2 KB

  char* Alds  = (char*)AldsV;
  char* Olds  = (char*)AldsV;      // overlay, valid after BAR4 of each tile
  char* Hlds  = (char*)HldsV;

  const int tid  = threadIdx.x;
  const int lane = tid & 63;
  const int wq   = lane >> 4;
  const int l16  = lane & 15;
  const int wave = tid >> 6;
  const int g    = tid & 15;
  const int s0   = tid >> 4;

  const int t0 = blockIdx.x * 2;
  const int t1 = t0 + 1;
  const bool has1 = (t1 < ntiles);

  const int c0 = wave * 32 + l16;
  const int c1 = c0 + 16;

  // ---- tile0 front: ea, idx, gather ----
  ealds[0][tid] = ea[t0 * 256 + tid];

  int idx0[8];
  #pragma unroll
  for (int it = 0; it < 8; ++it) {
    int seg = it * 16 + s0;
    idx0[it] = eidx[(seg & 1) * E + t0 * BM + (seg >> 1)];
  }
  int4 gv0[8];
  #pragma unroll
  for (int it = 0; it < 8; ++it)
    gv0[it] = *(const int4*)(xb + (size_t)idx0[it] * 128 + g * 8);

  // ---- hoisted scalars (once per block) ----
  const float bias0 = b1[c0], bias1 = b1[c1];
  const float w00 = W1[c0],       w01 = W1[128 + c0], w02 = W1[256 + c0], w03 = W1[384 + c0];
  const float w10 = W1[c1],       w11 = W1[128 + c1], w12 = W1[256 + c1], w13 = W1[384 + c1];
  const float bias20 = b2[c0], bias21 = b2[c1];

  // ---- layer-1 B fragments for tile0 ----
  bf16x8 bf1r[8][2];
  #pragma unroll
  for (int ks = 0; ks < 8; ++ks) {
    int kb = ks * 4 + wq;
    bf1r[ks][0] = __builtin_bit_cast(bf16x8, *(const int4*)(Bp1 + ((size_t)kb * 128 + c0) * 8));
    bf1r[ks][1] = __builtin_bit_cast(bf16x8, *(const int4*)(Bp1 + ((size_t)kb * 128 + c1) * 8));
  }

  // ---- stage A0 into LDS (XOR-swizzled dest, b128) ----
  #pragma unroll
  for (int it = 0; it < 8; ++it) {
    int seg = it * 16 + s0;
    int r = seg >> 1, half = seg & 1;
    int lofs = (r * 512 + half * 256 + g * 16) ^ ((r & 7) << 4);
    *(int4*)(Alds + lofs) = gv0[it];
  }
  __syncthreads();   // TOP0

  // ---- prefetch tile1 idx + ea (latency hides under tile0 L1) ----
  int idx1[8];
  if (has1) {
    #pragma unroll
    for (int it = 0; it < 8; ++it) {
      int seg = it * 16 + s0;
      idx1[it] = eidx[(seg & 1) * E + t1 * BM + (seg >> 1)];
    }
    ealds[1][tid] = ea[t1 * 256 + tid];
  }

  // ================= TILE 0 =================
  f32x4 acc[4][2];
  #pragma unroll
  for (int mf = 0; mf < 4; ++mf)
    #pragma unroll
    for (int rg = 0; rg < 4; ++rg) {
      int r = mf * 16 + wq * 4 + rg;
      float e0 = ealds[0][r * 4 + 0], e1 = ealds[0][r * 4 + 1];
      float e2 = ealds[0][r * 4 + 2], e3 = ealds[0][r * 4 + 3];
      acc[mf][0][rg] = bias0 + e0 * w00 + e1 * w01 + e2 * w02 + e3 * w03;
      acc[mf][1][rg] = bias1 + e0 * w10 + e1 * w11 + e2 * w12 + e3 * w13;
    }

  #pragma unroll
  for (int ks = 0; ks < 8; ++ks) {
    #pragma unroll
    for (int mf = 0; mf < 4; ++mf) {
      int r = mf * 16 + l16;
      int lofs = (r * 512 + ks * 64 + wq * 16) ^ ((r & 7) << 4);
      bf16x8 av = __builtin_bit_cast(bf16x8, *(const int4*)(Alds + lofs));
      acc[mf][0] = __builtin_amdgcn_mfma_f32_16x16x32_bf16(av, bf1r[ks][0], acc[mf][0], 0, 0, 0);
      acc[mf][1] = __builtin_amdgcn_mfma_f32_16x16x32_bf16(av, bf1r[ks][1], acc[mf][1], 0, 0, 0);
    }
  }

  // layer-2 B fragments (kept live across both tiles: 32 VGPR)
  bf16x8 bf2r[4][2];
  #pragma unroll
  for (int ks = 0; ks < 4; ++ks) {
    int kb = ks * 4 + wq;
    bf2r[ks][0] = __builtin_bit_cast(bf16x8, *(const int4*)(Bp2 + ((size_t)kb * 128 + c0) * 8));
    bf2r[ks][1] = __builtin_bit_cast(bf16x8, *(const int4*)(Bp2 + ((size_t)kb * 128 + c1) * 8));
  }

  asm volatile("s_waitcnt lgkmcnt(0)" ::: "memory");
  __builtin_amdgcn_s_barrier();    // BAR2: A0 reads done

  // ---- issue tile1 gather NOW (VGPR); hides under H/L2/O/NT (~1500+ cyc) ----
  int4 gv1[8];
  if (has1) {
    #pragma unroll
    for (int it = 0; it < 8; ++it)
      gv1[it] = *(const int4*)(xb + (size_t)idx1[it] * 128 + g * 8);
  }

  // ---- ReLU + h0 -> Hlds ----
  #pragma unroll
  for (int mf = 0; mf < 4; ++mf)
    #pragma unroll
    for (int nf = 0; nf < 2; ++nf) {
      int c = wave * 32 + nf * 16 + l16;
      #pragma unroll
      for (int rg = 0; rg < 4; ++rg) {
        int r = mf * 16 + wq * 4 + rg;
        float v = fmaxf(acc[mf][nf][rg], 0.0f);
        int lofs = (r * 256 + c * 2) ^ ((r & 7) << 4);
        *(unsigned short*)(Hlds + lofs) = f2bf(v);
      }
    }
  asm volatile("s_waitcnt lgkmcnt(0)" ::: "memory");
  __builtin_amdgcn_s_barrier();    // BAR3: H0 visible

  f32x4 acc2[4][2];
  #pragma unroll
  for (int mf = 0; mf < 4; ++mf) {
    acc2[mf][0] = (f32x4){bias20, bias20, bias20, bias20};
    acc2[mf][1] = (f32x4){bias21, bias21, bias21, bias21};
  }
  #pragma unroll
  for (int ks = 0; ks < 4; ++ks) {
    #pragma unroll
    for (int mf = 0; mf < 4; ++mf) {
      int r = mf * 16 + l16;
      int lofs = (r * 256 + ks * 64 + wq * 16) ^ ((r & 7) << 4);
      bf16x8 av = __builtin_bit_cast(bf16x8, *(const int4*)(Hlds + lofs));
      acc2[mf][0] = __builtin_amdgcn_mfma_f32_16x16x32_bf16(av, bf2r[ks][0], acc2[mf][0], 0, 0, 0);
      acc2[mf][1] = __builtin_amdgcn_mfma_f32_16x16x32_bf16(av, bf2r[ks][1], acc2[mf][1], 0, 0, 0);
    }
  }
  asm volatile("s_waitcnt lgkmcnt(0)" ::: "memory");
  __builtin_amdgcn_s_barrier();    // BAR4: H0 reads done (A0 reads done since BAR2) -> O overlay safe

  // ---- O0 -> Alds overlay (swizzled [64][128] f32) ----
  #pragma unroll
  for (int mf = 0; mf < 4; ++mf)
    #pragma unroll
    for (int nf = 0; nf < 2; ++nf) {
      int c = wave * 32 + nf * 16 + l16;
      #pragma unroll
      for (int rg = 0; rg < 4; ++rg) {
        int r = mf * 16 + wq * 4 + rg;
        int bofs = (r * 512 + c * 4) ^ ((r & 7) << 4);
        *(float*)(Olds + bofs) = acc2[mf][nf][rg];
      }
    }
  asm volatile("s_waitcnt lgkmcnt(0)" ::: "memory");
  __builtin_amdgcn_s_barrier();    // BAR5: O0 visible

  // ---- NT full-line stores tile0 ----
  {
    float* outbase = outp + (size_t)t0 * BM * 128;
    #pragma unroll
    for (int p = 0; p < 8; ++p) {
      int i = p * 256 + tid;
      int r = i >> 5, c4 = i & 31;
      int bofs = (r * 512 + c4 * 16) ^ ((r & 7) << 4);
      f32x4 v = *(const f32x4*)(Olds + bofs);
      __builtin_nontemporal_store(v, (f32x4*)(outbase + i * 4));
    }
  }

  // ================= TILE 1 =================
  if (has1) {
    asm volatile("s_waitcnt lgkmcnt(0)" ::: "memory");
    __builtin_amdgcn_s_barrier();  // BAR6: all O0 ds_reads done -> A1 write safe

    // stage A1 (gv1 arrived long ago; compiler inserts vmcnt wait)
    #pragma unroll
    for (int it = 0; it < 8; ++it) {
      int seg = it * 16 + s0;
      int r = seg >> 1, half = seg & 1;
      int lofs = (r * 512 + half * 256 + g * 16) ^ ((r & 7) << 4);
      *(int4*)(Alds + lofs) = gv1[it];
    }

    // reload layer-1 B fragments (L2-hit; hides under barrier + acc init)
    #pragma unroll
    for (int ks = 0; ks < 8; ++ks) {
      int kb = ks * 4 + wq;
      bf1r[ks][0] = __builtin_bit_cast(bf16x8, *(const int4*)(Bp1 + ((size_t)kb * 128 + c0) * 8));
      bf1r[ks][1] = __builtin_bit_cast(bf16x8, *(const int4*)(Bp1 + ((size_t)kb * 128 + c1) * 8));
    }

    asm volatile("s_waitcnt lgkmcnt(0)" ::: "memory");
    __builtin_amdgcn_s_barrier();  // TOP1: A1 visible

    #pragma unroll
    for (int mf = 0; mf < 4; ++mf)
      #pragma unroll
      for (int rg = 0; rg < 4; ++rg) {
        int r = mf * 16 + wq * 4 + rg;
        float e0 = ealds[1][r * 4 + 0], e1 = ealds[1][r * 4 + 1];
        float e2 = ealds[1][r * 4 + 2], e3 = ealds[1][r * 4 + 3];
        acc[mf][0][rg] = bias0 + e0 * w00 + e1 * w01 + e2 * w02 + e3 * w03;
        acc[mf][1][rg] = bias1 + e0 * w10 + e1 * w11 + e2 * w12 + e3 * w13;
      }

    #pragma unroll
    for (int ks = 0; ks < 8; ++ks) {
      #pragma unroll
      for (int mf = 0; mf < 4; ++mf) {
        int r = mf * 16 + l16;
        int lofs = (r * 512 + ks * 64 + wq * 16) ^ ((r & 7) << 4);
        bf16x8 av = __builtin_bit_cast(bf16x8, *(const int4*)(Alds + lofs));
        acc[mf][0] = __builtin_amdgcn_mfma_f32_16x16x32_bf16(av, bf1r[ks][0], acc[mf][0], 0, 0, 0);
        acc[mf][1] = __builtin_amdgcn_mfma_f32_16x16x32_bf16(av, bf1r[ks][1], acc[mf][1], 0, 0, 0);
      }
    }

    asm volatile("s_waitcnt lgkmcnt(0)" ::: "memory");
    __builtin_amdgcn_s_barrier();  // BAR2b: A1 reads done

    #pragma unroll
    for (int mf = 0; mf < 4; ++mf)
      #pragma unroll
      for (int nf = 0; nf < 2; ++nf) {
        int c = wave * 32 + nf * 16 + l16;
        #pragma unroll
        for (int rg = 0; rg < 4; ++rg) {
          int r = mf * 16 + wq * 4 + rg;
          float v = fmaxf(acc[mf][nf][rg], 0.0f);
          int lofs = (r * 256 + c * 2) ^ ((r & 7) << 4);
          *(unsigned short*)(Hlds + lofs) = f2bf(v);
        }
      }
    asm volatile("s_waitcnt lgkmcnt(0)" ::: "memory");
    __builtin_amdgcn_s_barrier();  // BAR3b: H1 visible

    f32x4 acc2b[4][2];
    #pragma unroll
    for (int mf = 0; mf < 4; ++mf) {
      acc2b[mf][0] = (f32x4){bias20, bias20, bias20, bias20};
      acc2b[mf][1] = (f32x4){bias21, bias21, bias21, bias21};
    }
    #pragma unroll
    for (int ks = 0; ks < 4; ++ks) {
      #pragma unroll
      for (int mf = 0; mf < 4; ++mf) {
        int r = mf * 16 + l16;
        int lofs = (r * 256 + ks * 64 + wq * 16) ^ ((r & 7) << 4);
        bf16x8 av = __builtin_bit_cast(bf16x8, *(const int4*)(Hlds + lofs));
        acc2b[mf][0] = __builtin_amdgcn_mfma_f32_16x16x32_bf16(av, bf2r[ks][0], acc2b[mf][0], 0, 0, 0);
        acc2b[mf][1] = __builtin_amdgcn_mfma_f32_16x16x32_bf16(av, bf2r[ks][1], acc2b[mf][1], 0, 0, 0);
      }
    }
    asm volatile("s_waitcnt lgkmcnt(0)" ::: "memory");
    __builtin_amdgcn_s_barrier();  // BAR4b: A1/H1 reads done -> O overlay safe

    #pragma unroll
    for (int mf = 0; mf < 4; ++mf)
      #pragma unroll
      for (int nf = 0; nf < 2; ++nf) {
        int c = wave * 32 + nf * 16 + l16;
        #pragma unroll
        for (int rg = 0; rg < 4; ++rg) {
          int r = mf * 16 + wq * 4 + rg;
          int bofs = (r * 512 + c * 4) ^ ((r & 7) << 4);
          *(float*)(Olds + bofs) = acc2b[mf][nf][rg];
        }
      }
    asm volatile("s_waitcnt lgkmcnt(0)" ::: "memory");
    __builtin_amdgcn_s_barrier();  // BAR5b: O1 visible

    float* outbase = outp + (size_t)t1 * BM * 128;
    #pragma unroll
    for (int p = 0; p < 8; ++p) {
      int i = p * 256 + tid;
      int r = i >> 5, c4 = i & 31;
      int bofs = (r * 512 + c4 * 16) ^ ((r & 7) << 4);
      f32x4 v = *(const f32x4*)(Olds + bofs);
      __builtin_nontemporal_store(v, (f32x4*)(outbase + i * 4));
    }
  }
}

// ---------------- fallback (fp32 gather, fused, 3/CU) for small ws ----------------
__global__ __launch_bounds__(256, 3)
void edge_fused_f32(const float* __restrict__ xf,
                    const float* __restrict__ ea, const int* __restrict__ eidx,
                    const float* __restrict__ W1, const float* __restrict__ b1,
                    const float* __restrict__ b2,
                    const unsigned short* __restrict__ Bp1, const unsigned short* __restrict__ Bp2,
                    float* __restrict__ outp, int E) {
  __shared__ int4 AldsV[2048];
  __shared__ int4 HldsV[1024];
  __shared__ float ealds[256];
  char* Alds = (char*)AldsV;
  char* Hlds = (char*)HldsV;

  const int tid  = threadIdx.x;
  const int lane = tid & 63;
  const int wq   = lane >> 4;
  const int l16  = lane & 15;
  const int wave = tid >> 6;
  const int g    = tid & 15;
  const int s0   = tid >> 4;
  const int eb   = blockIdx.x * BM;

  ealds[tid] = ea[eb * 4 + tid];

  int idxv[8];
  #pragma unroll
  for (int it = 0; it < 8; ++it) {
    int seg = it * 16 + s0;
    idxv[it] = eidx[(seg & 1) * E + eb + (seg >> 1)];
  }

  float4 ga[8], gb[8];
  #pragma unroll
  for (int it = 0; it < 8; ++it) {
    const float* src = xf + (size_t)idxv[it] * 128 + g * 8;
    ga[it] = *(const float4*)src;
    gb[it] = *(const float4*)(src + 4);
  }

  const int c0 = wave * 32 + l16;
  const int c1 = c0 + 16;
  const float bias0 = b1[c0], bias1 = b1[c1];
  const float w00 = W1[c0],       w01 = W1[128 + c0], w02 = W1[256 + c0], w03 = W1[384 + c0];
  const float w10 = W1[c1],       w11 = W1[128 + c1], w12 = W1[256 + c1], w13 = W1[384 + c1];
  const float bias20 = b2[c0], bias21 = b2[c1];

  bf16x8 bf1r[8][2];
  #pragma unroll
  for (int ks = 0; ks < 8; ++ks) {
    int kb = ks * 4 + wq;
    bf1r[ks][0] = __builtin_bit_cast(bf16x8, *(const int4*)(Bp1 + ((size_t)kb * 128 + c0) * 8));
    bf1r[ks][1] = __builtin_bit_cast(bf16x8, *(const int4*)(Bp1 + ((size_t)kb * 128 + c1) * 8));
  }

  #pragma unroll
  for (int it = 0; it < 8; ++it) {
    int seg = it * 16 + s0;
    int r = seg >> 1, half = seg & 1;
    int lofs = (r * 512 + half * 256 + g * 16) ^ ((r & 7) << 4);
    unsigned short h[8] = {f2bf(ga[it].x), f2bf(ga[it].y), f2bf(ga[it].z), f2bf(ga[it].w),
                           f2bf(gb[it].x), f2bf(gb[it].y), f2bf(gb[it].z), f2bf(gb[it].w)};
    int4 pk; __builtin_memcpy(&pk, h, 16);
    *(int4*)(Alds + lofs) = pk;
  }
  __syncthreads();

  f32x4 acc[4][2];
  #pragma unroll
  for (int mf = 0; mf < 4; ++mf)
    #pragma unroll
    for (int rg = 0; rg < 4; ++rg) {
      int r = mf * 16 + wq * 4 + rg;
      float e0 = ealds[r * 4 + 0], e1 = ealds[r * 4 + 1];
      float e2 = ealds[r * 4 + 2], e3 = ealds[r * 4 + 3];
      acc[mf][0][rg] = bias0 + e0 * w00 + e1 * w01 + e2 * w02 + e3 * w03;
      acc[mf][1][rg] = bias1 + e0 * w10 + e1 * w11 + e2 * w12 + e3 * w13;
    }

  #pragma unroll
  for (int ks = 0; ks < 8; ++ks)
    #pragma unroll
    for (int mf = 0; mf < 4; ++mf) {
      int r = mf * 16 + l16;
      int lofs = (r * 512 + ks * 64 + wq * 16) ^ ((r & 7) << 4);
      bf16x8 av = __builtin_bit_cast(bf16x8, *(const int4*)(Alds + lofs));
      acc[mf][0] = __builtin_amdgcn_mfma_f32_16x16x32_bf16(av, bf1r[ks][0], acc[mf][0], 0, 0, 0);
      acc[mf][1] = __builtin_amdgcn_mfma_f32_16x16x32_bf16(av, bf1r[ks][1], acc[mf][1], 0, 0, 0);
    }

  bf16x8 bf2r[4][2];
  #pragma unroll
  for (int ks = 0; ks < 4; ++ks) {
    int kb = ks * 4 + wq;
    bf2r[ks][0] = __builtin_bit_cast(bf16x8, *(const int4*)(Bp2 + ((size_t)kb * 128 + c0) * 8));
    bf2r[ks][1] = __builtin_bit_cast(bf16x8, *(const int4*)(Bp2 + ((size_t)kb * 128 + c1) * 8));
  }

  #pragma unroll
  for (int mf = 0; mf < 4; ++mf)
    #pragma unroll
    for (int nf = 0; nf < 2; ++nf) {
      int c = wave * 32 + nf * 16 + l16;
      #pragma unroll
      for (int rg = 0; rg < 4; ++rg) {
        int r = mf * 16 + wq * 4 + rg;
        float v = fmaxf(acc[mf][nf][rg], 0.0f);
        int lofs = (r * 256 + c * 2) ^ ((r & 7) << 4);
        *(unsigned short*)(Hlds + lofs) = f2bf(v);
      }
    }
  __syncthreads();

  f32x4 acc2[4][2];
  #pragma unroll
  for (int mf = 0; mf < 4; ++mf) {
    acc2[mf][0] = (f32x4){bias20, bias20, bias20, bias20};
    acc2[mf][1] = (f32x4){bias21, bias21, bias21, bias21};
  }
  #pragma unroll
  for (int ks = 0; ks < 4; ++ks)
    #pragma unroll
    for (int mf = 0; mf < 4; ++mf) {
      int r = mf * 16 + l16;
      int lofs = (r * 256 + ks * 64 + wq * 16) ^ ((r & 7) << 4);
      bf16x8 av = __builtin_bit_cast(bf16x8, *(const int4*)(Hlds + lofs));
      acc2[mf][0] = __builtin_amdgcn_mfma_f32_16x16x32_bf16(av, bf2r[ks][0], acc2[mf][0], 0, 0, 0);
      acc2[mf][1] = __builtin_amdgcn_mfma_f32_16x16x32_bf16(av, bf2r[ks][1], acc2[mf][1], 0, 0, 0);
    }

  #pragma unroll
  for (int mf = 0; mf < 4; ++mf)
    #pragma unroll
    for (int nf = 0; nf < 2; ++nf) {
      int c = wave * 32 + nf * 16 + l16;
      #pragma unroll
      for (int rg = 0; rg < 4; ++rg) {
        int r = mf * 16 + wq * 4 + rg;
        outp[(size_t)(eb + r) * 128 + c] = acc2[mf][nf][rg];
      }
    }
}

extern "C" void kernel_launch(void* const* d_in, const int* in_sizes, int n_in,
                              void* d_out, int out_size, void* d_ws, size_t ws_size,
                              hipStream_t stream) {
  const float* x  = (const float*)d_in[0];
  const float* ea = (const float*)d_in[1];
  const int* eidx = (const int*)d_in[2];
  const float* W1 = (const float*)d_in[3];
  const float* b1 = (const float*)d_in[4];
  const float* W2 = (const float*)d_in[5];
  const float* b2 = (const float*)d_in[6];
  float* outp = (float*)d_out;

  const int E = in_sizes[2] / 2;
  const int nnodes = in_sizes[0] / 128;
  const int ntiles = E / BM;

  unsigned short* Bp1 = (unsigned short*)d_ws;           // 64 KB
  unsigned short* Bp2 = Bp1 + 32768;                     // 32 KB
  unsigned short* xb  = (unsigned short*)((char*)d_ws + 98304);
  const size_t need = 98304 + (size_t)nnodes * 128 * 2;

  pack_w_kernel<<<192, 256, 0, stream>>>(W1, W2, Bp1, Bp2);

  if (ws_size >= need) {
    int n8 = nnodes * 128 / 8;
    convert_x_kernel<<<(n8 + 255) / 256, 256, 0, stream>>>(x, xb, n8);
    int nblk = (ntiles + 1) / 2;
    edge_nt_x2<<<nblk, 256, 0, stream>>>(xb, ea, eidx, W1, b1, b2, Bp1, Bp2, outp, E, ntiles);
  } else {
    edge_fused_f32<<<ntiles, 256, 0, stream>>>(x, ea, eidx, W1, b1, b2, Bp1, Bp2, outp, E);
  }
}

// Round 19
// 155.740 us; speedup vs baseline: 3.0529x; 3.0529x over previous
//
#include <hip/hip_runtime.h>
#include <hip/hip_bf16.h>

typedef __attribute__((ext_vector_type(4))) float f32x4;
typedef __attribute__((ext_vector_type(8))) short bf16x8;

__device__ __forceinline__ unsigned short f2bf(float f) {
  union { float f; unsigned int u; } v; v.f = f;
  unsigned int u = v.u;
  unsigned int r = (u + 0x7FFFu + ((u >> 16) & 1u)) >> 16;  // RNE
  return (unsigned short)r;
}

// ---------------- prep: pack W1(rows 4..260) and W2 into MFMA-B fragment order ----
__global__ void pack_w_kernel(const float* __restrict__ W1, const float* __restrict__ W2,
                              unsigned short* __restrict__ Bp1, unsigned short* __restrict__ Bp2) {
  int p = blockIdx.x * 256 + threadIdx.x;
  if (p < 32768) {                      // 256x128 for layer 1 (W1 rows 4..260)
    int j = p & 7, n = (p >> 3) & 127, kb = p >> 10;
    Bp1[p] = f2bf(W1[(4 + kb * 8 + j) * 128 + n]);
  } else if (p < 49152) {               // 128x128 for layer 2
    int q = p - 32768;
    int j = q & 7, n = (q >> 3) & 127, kb = q >> 10;
    Bp2[q] = f2bf(W2[(kb * 8 + j) * 128 + n]);
  }
}

// ---------------- prep: x fp32 -> bf16 ----------------
__global__ void convert_x_kernel(const float* __restrict__ x, unsigned short* __restrict__ xb, int n8) {
  int i = blockIdx.x * blockDim.x + threadIdx.x;
  if (i >= n8) return;
  const float4* s = (const float4*)x + (size_t)i * 2;
  float4 a = s[0], b = s[1];
  unsigned short h[8] = {f2bf(a.x), f2bf(a.y), f2bf(a.z), f2bf(a.w),
                         f2bf(b.x), f2bf(b.y), f2bf(b.z), f2bf(b.w)};
  int4 pk; __builtin_memcpy(&pk, h, 16);
  ((int4*)xb)[i] = pk;
}

constexpr int BM = 64;

// ---------------- main kernel: one 64-edge tile per block, 512 threads (8 waves) ----
// R16's exact memory geometry (10000 blocks, 49 KB LDS, one 32 KB output tile per
// block, NT full-line epilogue, staged normal-load gather) — the ONLY clean-traffic
// basin found in R1-R18 (any widening of the concurrent output window amplifies
// WRITE 2-4x). The single change vs R16: 512 threads per block, each wave owns 16
// output columns (not 32). Per-block work/access pattern is bit-identical; waves/CU
// rises 12 -> 16-24 for pure latency hiding. Per-wave VGPR roughly halves
// (bf1r[8], acc[4], acc2[4]) making 8 waves feasible.
__global__ __launch_bounds__(512, 4)
void edge_nt512(const unsigned short* __restrict__ xb,
                const float* __restrict__ ea, const int* __restrict__ eidx,
                const float* __restrict__ W1, const float* __restrict__ b1,
                const float* __restrict__ b2,
                const unsigned short* __restrict__ Bp1, const unsigned short* __restrict__ Bp2,
                float* __restrict__ outp, int E) {
  __shared__ int4 AldsV[2048];   // 32 KB: A-tile [64][256] bf16 swizzled; O-stage overlays (swizzled [64][128] f32)
  __shared__ int4 HldsV[1024];   // 16 KB: h [64][128] bf16 swizzled
  __shared__ float ealds[256];   // 64 edges x 4 attrs

  char* Alds = (char*)AldsV;
  char* Olds = (char*)AldsV;     // overlay, written after post-H barrier (all A-reads done)
  char* Hlds = (char*)HldsV;

  const int tid  = threadIdx.x;
  const int lane = tid & 63;
  const int wq   = lane >> 4;
  const int l16  = lane & 15;
  const int wave = tid >> 6;     // 0..7
  const int g    = tid & 15;
  const int s0   = tid >> 4;     // 0..31
  const int eb   = blockIdx.x * BM;

  // ---- issue independent loads first: edge_attr, eidx ----
  if (tid < 256) ealds[tid] = ea[eb * 4 + tid];

  int idxv[4];
  #pragma unroll
  for (int it = 0; it < 4; ++it) {
    int seg = it * 32 + s0;                 // 0..127
    idxv[it] = eidx[(seg & 1) * E + eb + (seg >> 1)];
  }

  // ---- gather loads: normal (L2-allocating) int4 loads into VGPRs ----
  int4 gv[4];
  #pragma unroll
  for (int it = 0; it < 4; ++it)
    gv[it] = *(const int4*)(xb + (size_t)idxv[it] * 128 + g * 8);

  const int c0 = wave * 16 + l16;           // each wave owns 16 output columns

  // ---- hoisted scalars + layer-1 B fragments (latency overlaps gather) ----
  const float bias0 = b1[c0];
  const float w00 = W1[c0], w01 = W1[128 + c0], w02 = W1[256 + c0], w03 = W1[384 + c0];
  const float bias20 = b2[c0];

  bf16x8 bf1r[8];
  #pragma unroll
  for (int ks = 0; ks < 8; ++ks) {
    int kb = ks * 4 + wq;
    bf1r[ks] = __builtin_bit_cast(bf16x8, *(const int4*)(Bp1 + ((size_t)kb * 128 + c0) * 8));
  }

  // ---- stage gather into LDS (XOR-swizzled dest, b128 writes) ----
  #pragma unroll
  for (int it = 0; it < 4; ++it) {
    int seg = it * 32 + s0;
    int r = seg >> 1, half = seg & 1;
    int lofs = (r * 512 + half * 256 + g * 16) ^ ((r & 7) << 4);
    *(int4*)(Alds + lofs) = gv[it];
  }
  __syncthreads();   // TOP

  // ---- layer 1 accumulator init: b1 + edge_attr x W1[0:4] in fp32 ----
  f32x4 acc[4];
  #pragma unroll
  for (int mf = 0; mf < 4; ++mf)
    #pragma unroll
    for (int rg = 0; rg < 4; ++rg) {
      int r = mf * 16 + wq * 4 + rg;
      float e0 = ealds[r * 4 + 0], e1 = ealds[r * 4 + 1];
      float e2 = ealds[r * 4 + 2], e3 = ealds[r * 4 + 3];
      acc[mf][rg] = bias0 + e0 * w00 + e1 * w01 + e2 * w02 + e3 * w03;
    }

  // ---- layer 1 MFMA: K = 256 (sender 128 | receiver 128), B from registers ----
  #pragma unroll
  for (int ks = 0; ks < 8; ++ks) {
    #pragma unroll
    for (int mf = 0; mf < 4; ++mf) {
      int r = mf * 16 + l16;
      int lofs = (r * 512 + ks * 64 + wq * 16) ^ ((r & 7) << 4);
      bf16x8 av = __builtin_bit_cast(bf16x8, *(const int4*)(Alds + lofs));
      acc[mf] = __builtin_amdgcn_mfma_f32_16x16x32_bf16(av, bf1r[ks], acc[mf], 0, 0, 0);
    }
  }

  // ---- layer-2 B fragments: issue now, latency hides under H-write + barrier ----
  bf16x8 bf2r[4];
  #pragma unroll
  for (int ks = 0; ks < 4; ++ks) {
    int kb = ks * 4 + wq;
    bf2r[ks] = __builtin_bit_cast(bf16x8, *(const int4*)(Bp2 + ((size_t)kb * 128 + c0) * 8));
  }

  // ---- ReLU + h -> Hlds (bf16, swizzled) ----
  #pragma unroll
  for (int mf = 0; mf < 4; ++mf)
    #pragma unroll
    for (int rg = 0; rg < 4; ++rg) {
      int r = mf * 16 + wq * 4 + rg;
      float v = fmaxf(acc[mf][rg], 0.0f);
      int lofs = (r * 256 + c0 * 2) ^ ((r & 7) << 4);
      *(unsigned short*)(Hlds + lofs) = f2bf(v);
    }
  __syncthreads();   // post-H: H visible; all A-reads done -> O overlay safe after layer 2

  // ---- layer 2: K = 128 ----
  f32x4 acc2[4];
  #pragma unroll
  for (int mf = 0; mf < 4; ++mf)
    acc2[mf] = (f32x4){bias20, bias20, bias20, bias20};
  #pragma unroll
  for (int ks = 0; ks < 4; ++ks) {
    #pragma unroll
    for (int mf = 0; mf < 4; ++mf) {
      int r = mf * 16 + l16;
      int lofs = (r * 256 + ks * 64 + wq * 16) ^ ((r & 7) << 4);
      bf16x8 hv = __builtin_bit_cast(bf16x8, *(const int4*)(Hlds + lofs));
      acc2[mf] = __builtin_amdgcn_mfma_f32_16x16x32_bf16(hv, bf2r[ks], acc2[mf], 0, 0, 0);
    }
  }

  // ---- stage acc2 -> Alds overlay (swizzled [64][128] f32; writes disjoint from H) ----
  #pragma unroll
  for (int mf = 0; mf < 4; ++mf)
    #pragma unroll
    for (int rg = 0; rg < 4; ++rg) {
      int r = mf * 16 + wq * 4 + rg;
      int bofs = (r * 512 + c0 * 4) ^ ((r & 7) << 4);
      *(float*)(Olds + bofs) = acc2[mf][rg];
    }
  __syncthreads();   // post-O: O visible

  // ---- epilogue: contiguous NT full-line stores (1024 B per wave-instruction) ----
  float* outbase = outp + (size_t)eb * 128;
  #pragma unroll
  for (int p = 0; p < 4; ++p) {
    int i = p * 512 + tid;            // float4 index within the 64x128 tile
    int r = i >> 5, c4 = i & 31;      // 32 float4 per row
    int bofs = (r * 512 + c4 * 16) ^ ((r & 7) << 4);
    f32x4 v = *(const f32x4*)(Olds + bofs);
    __builtin_nontemporal_store(v, (f32x4*)(outbase + i * 4));
  }
}

// ---------------- fallback (fp32 gather, fused, 3/CU) for small ws ----------------
__global__ __launch_bounds__(256, 3)
void edge_fused_f32(const float* __restrict__ xf,
                    const float* __restrict__ ea, const int* __restrict__ eidx,
                    const float* __restrict__ W1, const float* __restrict__ b1,
                    const float* __restrict__ b2,
                    const unsigned short* __restrict__ Bp1, const unsigned short* __restrict__ Bp2,
                    float* __restrict__ outp, int E) {
  __shared__ int4 AldsV[2048];
  __shared__ int4 HldsV[1024];
  __shared__ float ealds[256];
  char* Alds = (char*)AldsV;
  char* Hlds = (char*)HldsV;

  const int tid  = threadIdx.x;
  const int lane = tid & 63;
  const int wq   = lane >> 4;
  const int l16  = lane & 15;
  const int wave = tid >> 6;
  const int g    = tid & 15;
  const int s0   = tid >> 4;
  const int eb   = blockIdx.x * BM;

  ealds[tid] = ea[eb * 4 + tid];

  int idxv[8];
  #pragma unroll
  for (int it = 0; it < 8; ++it) {
    int seg = it * 16 + s0;
    idxv[it] = eidx[(seg & 1) * E + eb + (seg >> 1)];
  }

  float4 ga[8], gb[8];
  #pragma unroll
  for (int it = 0; it < 8; ++it) {
    const float* src = xf + (size_t)idxv[it] * 128 + g * 8;
    ga[it] = *(const float4*)src;
    gb[it] = *(const float4*)(src + 4);
  }

  const int c0 = wave * 32 + l16;
  const int c1 = c0 + 16;
  const float bias0 = b1[c0], bias1 = b1[c1];
  const float w00 = W1[c0],       w01 = W1[128 + c0], w02 = W1[256 + c0], w03 = W1[384 + c0];
  const float w10 = W1[c1],       w11 = W1[128 + c1], w12 = W1[256 + c1], w13 = W1[384 + c1];
  const float bias20 = b2[c0], bias21 = b2[c1];

  bf16x8 bf1r[8][2];
  #pragma unroll
  for (int ks = 0; ks < 8; ++ks) {
    int kb = ks * 4 + wq;
    bf1r[ks][0] = __builtin_bit_cast(bf16x8, *(const int4*)(Bp1 + ((size_t)kb * 128 + c0) * 8));
    bf1r[ks][1] = __builtin_bit_cast(bf16x8, *(const int4*)(Bp1 + ((size_t)kb * 128 + c1) * 8));
  }

  #pragma unroll
  for (int it = 0; it < 8; ++it) {
    int seg = it * 16 + s0;
    int r = seg >> 1, half = seg & 1;
    int lofs = (r * 512 + half * 256 + g * 16) ^ ((r & 7) << 4);
    unsigned short h[8] = {f2bf(ga[it].x), f2bf(ga[it].y), f2bf(ga[it].z), f2bf(ga[it].w),
                           f2bf(gb[it].x), f2bf(gb[it].y), f2bf(gb[it].z), f2bf(gb[it].w)};
    int4 pk; __builtin_memcpy(&pk, h, 16);
    *(int4*)(Alds + lofs) = pk;
  }
  __syncthreads();

  f32x4 acc[4][2];
  #pragma unroll
  for (int mf = 0; mf < 4; ++mf)
    #pragma unroll
    for (int rg = 0; rg < 4; ++rg) {
      int r = mf * 16 + wq * 4 + rg;
      float e0 = ealds[r * 4 + 0], e1 = ealds[r * 4 + 1];
      float e2 = ealds[r * 4 + 2], e3 = ealds[r * 4 + 3];
      acc[mf][0][rg] = bias0 + e0 * w00 + e1 * w01 + e2 * w02 + e3 * w03;
      acc[mf][1][rg] = bias1 + e0 * w10 + e1 * w11 + e2 * w12 + e3 * w13;
    }

  #pragma unroll
  for (int ks = 0; ks < 8; ++ks)
    #pragma unroll
    for (int mf = 0; mf < 4; ++mf) {
      int r = mf * 16 + l16;
      int lofs = (r * 512 + ks * 64 + wq * 16) ^ ((r & 7) << 4);
      bf16x8 av = __builtin_bit_cast(bf16x8, *(const int4*)(Alds + lofs));
      acc[mf][0] = __builtin_amdgcn_mfma_f32_16x16x32_bf16(av, bf1r[ks][0], acc[mf][0], 0, 0, 0);
      acc[mf][1] = __builtin_amdgcn_mfma_f32_16x16x32_bf16(av, bf1r[ks][1], acc[mf][1], 0, 0, 0);
    }

  bf16x8 bf2r[4][2];
  #pragma unroll
  for (int ks = 0; ks < 4; ++ks) {
    int kb = ks * 4 + wq;
    bf2r[ks][0] = __builtin_bit_cast(bf16x8, *(const int4*)(Bp2 + ((size_t)kb * 128 + c0) * 8));
    bf2r[ks][1] = __builtin_bit_cast(bf16x8, *(const int4*)(Bp2 + ((size_t)kb * 128 + c1) * 8));
  }

  #pragma unroll
  for (int mf = 0; mf < 4; ++mf)
    #pragma unroll
    for (int nf = 0; nf < 2; ++nf) {
      int c = wave * 32 + nf * 16 + l16;
      #pragma unroll
      for (int rg = 0; rg < 4; ++rg) {
        int r = mf * 16 + wq * 4 + rg;
        float v = fmaxf(acc[mf][nf][rg], 0.0f);
        int lofs = (r * 256 + c * 2) ^ ((r & 7) << 4);
        *(unsigned short*)(Hlds + lofs) = f2bf(v);
      }
    }
  __syncthreads();

  f32x4 acc2[4][2];
  #pragma unroll
  for (int mf = 0; mf < 4; ++mf) {
    acc2[mf][0] = (f32x4){bias20, bias20, bias20, bias20};
    acc2[mf][1] = (f32x4){bias21, bias21, bias21, bias21};
  }
  #pragma unroll
  for (int ks = 0; ks < 4; ++ks)
    #pragma unroll
    for (int mf = 0; mf < 4; ++mf) {
      int r = mf * 16 + l16;
      int lofs = (r * 256 + ks * 64 + wq * 16) ^ ((r & 7) << 4);
      bf16x8 av = __builtin_bit_cast(bf16x8, *(const int4*)(Hlds + lofs));
      acc2[mf][0] = __builtin_amdgcn_mfma_f32_16x16x32_bf16(av, bf2r[ks][0], acc2[mf][0], 0, 0, 0);
      acc2[mf][1] = __builtin_amdgcn_mfma_f32_16x16x32_bf16(av, bf2r[ks][1], acc2[mf][1], 0, 0, 0);
    }

  #pragma unroll
  for (int mf = 0; mf < 4; ++mf)
    #pragma unroll
    for (int nf = 0; nf < 2; ++nf) {
      int c = wave * 32 + nf * 16 + l16;
      #pragma unroll
      for (int rg = 0; rg < 4; ++rg) {
        int r = mf * 16 + wq * 4 + rg;
        outp[(size_t)(eb + r) * 128 + c] = acc2[mf][nf][rg];
      }
    }
}

extern "C" void kernel_launch(void* const* d_in, const int* in_sizes, int n_in,
                              void* d_out, int out_size, void* d_ws, size_t ws_size,
                              hipStream_t stream) {
  const float* x  = (const float*)d_in[0];
  const float* ea = (const float*)d_in[1];
  const int* eidx = (const int*)d_in[2];
  const float* W1 = (const float*)d_in[3];
  const float* b1 = (const float*)d_in[4];
  const float* W2 = (const float*)d_in[5];
  const float* b2 = (const float*)d_in[6];
  float* outp = (float*)d_out;

  const int E = in_sizes[2] / 2;
  const int nnodes = in_sizes[0] / 128;
  const int ntiles = E / BM;

  unsigned short* Bp1 = (unsigned short*)d_ws;           // 64 KB
  unsigned short* Bp2 = Bp1 + 32768;                     // 32 KB
  unsigned short* xb  = (unsigned short*)((char*)d_ws + 98304);
  const size_t need = 98304 + (size_t)nnodes * 128 * 2;

  pack_w_kernel<<<192, 256, 0, stream>>>(W1, W2, Bp1, Bp2);

  if (ws_size >= need) {
    int n8 = nnodes * 128 / 8;
    convert_x_kernel<<<(n8 + 255) / 256, 256, 0, stream>>>(x, xb, n8);
    edge_nt512<<<ntiles, 512, 0, stream>>>(xb, ea, eidx, W1, b1, b2, Bp1, Bp2, outp, E);
  } else {
    edge_fused_f32<<<ntiles, 256, 0, stream>>>(x, ea, eidx, W1, b1, b2, Bp1, Bp2, outp, E);
  }
}

// Round 20
// 151.400 us; speedup vs baseline: 3.1404x; 1.0287x over previous
//
#include <hip/hip_runtime.h>
#include <hip/hip_bf16.h>

typedef __attribute__((ext_vector_type(4))) float f32x4;
typedef __attribute__((ext_vector_type(8))) short bf16x8;

__device__ __forceinline__ unsigned short f2bf(float f) {
  union { float f; unsigned int u; } v; v.f = f;
  unsigned int u = v.u;
  unsigned int r = (u + 0x7FFFu + ((u >> 16) & 1u)) >> 16;  // RNE
  return (unsigned short)r;
}

// ---------------- prep: pack W1(rows 4..260) and W2 into MFMA-B fragment order ----
__global__ void pack_w_kernel(const float* __restrict__ W1, const float* __restrict__ W2,
                              unsigned short* __restrict__ Bp1, unsigned short* __restrict__ Bp2) {
  int p = blockIdx.x * 256 + threadIdx.x;
  if (p < 32768) {                      // 256x128 for layer 1 (W1 rows 4..260)
    int j = p & 7, n = (p >> 3) & 127, kb = p >> 10;
    Bp1[p] = f2bf(W1[(4 + kb * 8 + j) * 128 + n]);
  } else if (p < 49152) {               // 128x128 for layer 2
    int q = p - 32768;
    int j = q & 7, n = (q >> 3) & 127, kb = q >> 10;
    Bp2[q] = f2bf(W2[(kb * 8 + j) * 128 + n]);
  }
}

constexpr int BM = 64;

// ---------------- main fused kernel: one 64-edge tile per block, 3 blocks/CU ----
// R16's exact structure and memory geometry (the ONLY clean-traffic basin in
// R1-R19: 10000 blocks x one 32 KB output tile, 3 blocks/CU, staged normal-load
// gather, NT full-line epilogue) with the convert_x pass FUSED away: gather reads
// x as fp32 (L3-resident, 51.2 MB) and converts to bf16 in-register during LDS
// staging (R9-validated code). Saves the ~14 us serial convert dispatch + xb
// write/read traffic. Occupancy axis is exhausted: 4/CU amplifies (R5/R6/R14/R17),
// 2-tile blocks amplify (R7/R18), 8-wave blocks regress (R19).
__global__ __launch_bounds__(256, 3)
void edge_fused_nt(const float* __restrict__ xf,
                   const float* __restrict__ ea, const int* __restrict__ eidx,
                   const float* __restrict__ W1, const float* __restrict__ b1,
                   const float* __restrict__ b2,
                   const unsigned short* __restrict__ Bp1, const unsigned short* __restrict__ Bp2,
                   float* __restrict__ outp, int E) {
  __shared__ int4 AldsV[2112];   // 33 KB: A-tile [64][256] bf16 swizzled; O-stage overlays ([64][132] f32 padded)
  __shared__ int4 HldsV[1024];   // 16 KB: h [64][128] bf16 swizzled
  __shared__ float ealds[256];   // 64 edges x 4 attrs

  char* Alds  = (char*)AldsV;
  float* Olds = (float*)AldsV;   // overlay, valid after the pre-layer-2 barrier
  char* Hlds  = (char*)HldsV;

  const int tid  = threadIdx.x;
  const int lane = tid & 63;
  const int wq   = lane >> 4;
  const int l16  = lane & 15;
  const int wave = tid >> 6;
  const int g    = tid & 15;
  const int s0   = tid >> 4;
  const int eb   = blockIdx.x * BM;

  // ---- issue independent loads first: edge_attr, eidx ----
  ealds[tid] = ea[eb * 4 + tid];

  int idxv[8];
  #pragma unroll
  for (int it = 0; it < 8; ++it) {
    int seg = it * 16 + s0;
    idxv[it] = eidx[(seg & 1) * E + eb + (seg >> 1)];
  }

  // ---- gather loads: normal (L2-allocating) fp32 loads into VGPRs ----
  float4 ga[8], gb[8];
  #pragma unroll
  for (int it = 0; it < 8; ++it) {
    const float* src = xf + (size_t)idxv[it] * 128 + g * 8;
    ga[it] = *(const float4*)src;
    gb[it] = *(const float4*)(src + 4);
  }

  const int c0 = wave * 32 + l16;
  const int c1 = c0 + 16;

  // ---- hoisted scalars + layer-1 B fragments (latency overlaps gather) ----
  const float bias0 = b1[c0], bias1 = b1[c1];
  const float w00 = W1[c0],       w01 = W1[128 + c0], w02 = W1[256 + c0], w03 = W1[384 + c0];
  const float w10 = W1[c1],       w11 = W1[128 + c1], w12 = W1[256 + c1], w13 = W1[384 + c1];
  const float bias20 = b2[c0], bias21 = b2[c1];

  bf16x8 bf1r[8][2];
  #pragma unroll
  for (int ks = 0; ks < 8; ++ks) {
    int kb = ks * 4 + wq;
    bf1r[ks][0] = __builtin_bit_cast(bf16x8, *(const int4*)(Bp1 + ((size_t)kb * 128 + c0) * 8));
    bf1r[ks][1] = __builtin_bit_cast(bf16x8, *(const int4*)(Bp1 + ((size_t)kb * 128 + c1) * 8));
  }

  // ---- convert fp32 -> bf16 and stage into LDS (XOR-swizzled dest, b128) ----
  #pragma unroll
  for (int it = 0; it < 8; ++it) {
    int seg = it * 16 + s0;
    int r = seg >> 1, half = seg & 1;
    int lofs = (r * 512 + half * 256 + g * 16) ^ ((r & 7) << 4);
    unsigned short h[8] = {f2bf(ga[it].x), f2bf(ga[it].y), f2bf(ga[it].z), f2bf(ga[it].w),
                           f2bf(gb[it].x), f2bf(gb[it].y), f2bf(gb[it].z), f2bf(gb[it].w)};
    int4 pk; __builtin_memcpy(&pk, h, 16);
    *(int4*)(Alds + lofs) = pk;
  }
  __syncthreads();

  // ---- layer 1 accumulator init: b1 + edge_attr x W1[0:4] in fp32 ----
  f32x4 acc[4][2];
  #pragma unroll
  for (int mf = 0; mf < 4; ++mf)
    #pragma unroll
    for (int rg = 0; rg < 4; ++rg) {
      int r = mf * 16 + wq * 4 + rg;
      float e0 = ealds[r * 4 + 0], e1 = ealds[r * 4 + 1];
      float e2 = ealds[r * 4 + 2], e3 = ealds[r * 4 + 3];
      acc[mf][0][rg] = bias0 + e0 * w00 + e1 * w01 + e2 * w02 + e3 * w03;
      acc[mf][1][rg] = bias1 + e0 * w10 + e1 * w11 + e2 * w12 + e3 * w13;
    }

  // ---- layer 1 MFMA: K = 256 (sender 128 | receiver 128), B from registers ----
  #pragma unroll
  for (int ks = 0; ks < 8; ++ks) {
    #pragma unroll
    for (int mf = 0; mf < 4; ++mf) {
      int r = mf * 16 + l16;
      int lofs = (r * 512 + ks * 64 + wq * 16) ^ ((r & 7) << 4);
      bf16x8 av = __builtin_bit_cast(bf16x8, *(const int4*)(Alds + lofs));
      acc[mf][0] = __builtin_amdgcn_mfma_f32_16x16x32_bf16(av, bf1r[ks][0], acc[mf][0], 0, 0, 0);
      acc[mf][1] = __builtin_amdgcn_mfma_f32_16x16x32_bf16(av, bf1r[ks][1], acc[mf][1], 0, 0, 0);
    }
  }

  // ---- layer-2 B fragments: issue now, latency hides under H-write + barrier ----
  bf16x8 bf2r[4][2];
  #pragma unroll
  for (int ks = 0; ks < 4; ++ks) {
    int kb = ks * 4 + wq;
    bf2r[ks][0] = __builtin_bit_cast(bf16x8, *(const int4*)(Bp2 + ((size_t)kb * 128 + c0) * 8));
    bf2r[ks][1] = __builtin_bit_cast(bf16x8, *(const int4*)(Bp2 + ((size_t)kb * 128 + c1) * 8));
  }

  // ---- ReLU + h -> LDS (bf16, swizzled) ----
  #pragma unroll
  for (int mf = 0; mf < 4; ++mf)
    #pragma unroll
    for (int nf = 0; nf < 2; ++nf) {
      int c = wave * 32 + nf * 16 + l16;
      #pragma unroll
      for (int rg = 0; rg < 4; ++rg) {
        int r = mf * 16 + wq * 4 + rg;
        float v = fmaxf(acc[mf][nf][rg], 0.0f);
        int lofs = (r * 256 + c * 2) ^ ((r & 7) << 4);
        *(unsigned short*)(Hlds + lofs) = f2bf(v);
      }
    }
  __syncthreads();   // after this barrier ALL waves are done reading Alds -> Olds overlay safe

  // ---- layer 2: K = 128 ----
  f32x4 acc2[4][2];
  #pragma unroll
  for (int mf = 0; mf < 4; ++mf) {
    acc2[mf][0] = (f32x4){bias20, bias20, bias20, bias20};
    acc2[mf][1] = (f32x4){bias21, bias21, bias21, bias21};
  }
  #pragma unroll
  for (int ks = 0; ks < 4; ++ks) {
    #pragma unroll
    for (int mf = 0; mf < 4; ++mf) {
      int r = mf * 16 + l16;
      int lofs = (r * 256 + ks * 64 + wq * 16) ^ ((r & 7) << 4);
      bf16x8 av = __builtin_bit_cast(bf16x8, *(const int4*)(Hlds + lofs));
      acc2[mf][0] = __builtin_amdgcn_mfma_f32_16x16x32_bf16(av, bf2r[ks][0], acc2[mf][0], 0, 0, 0);
      acc2[mf][1] = __builtin_amdgcn_mfma_f32_16x16x32_bf16(av, bf2r[ks][1], acc2[mf][1], 0, 0, 0);
    }
  }

  // ---- stage acc2 -> LDS f32 [64][132] (padded stride kills write conflicts) ----
  #pragma unroll
  for (int mf = 0; mf < 4; ++mf)
    #pragma unroll
    for (int nf = 0; nf < 2; ++nf) {
      int c = wave * 32 + nf * 16 + l16;
      #pragma unroll
      for (int rg = 0; rg < 4; ++rg) {
        int r = mf * 16 + wq * 4 + rg;
        Olds[r * 132 + c] = acc2[mf][nf][rg];
      }
    }
  __syncthreads();

  // ---- epilogue: contiguous NT full-line stores (1024 B per wave-instruction) ----
  float* outbase = outp + (size_t)eb * 128;
  #pragma unroll
  for (int p = 0; p < 8; ++p) {
    int i = p * 256 + tid;            // float4 index within the 64x128 tile
    int r = i >> 5, c4 = i & 31;      // 32 float4 per row
    f32x4 v = *(const f32x4*)(Olds + r * 132 + c4 * 4);
    __builtin_nontemporal_store(v, (f32x4*)(outbase + i * 4));
  }
}

extern "C" void kernel_launch(void* const* d_in, const int* in_sizes, int n_in,
                              void* d_out, int out_size, void* d_ws, size_t ws_size,
                              hipStream_t stream) {
  const float* x  = (const float*)d_in[0];
  const float* ea = (const float*)d_in[1];
  const int* eidx = (const int*)d_in[2];
  const float* W1 = (const float*)d_in[3];
  const float* b1 = (const float*)d_in[4];
  const float* W2 = (const float*)d_in[5];
  const float* b2 = (const float*)d_in[6];
  float* outp = (float*)d_out;

  const int E = in_sizes[2] / 2;
  const int ntiles = E / BM;

  unsigned short* Bp1 = (unsigned short*)d_ws;           // 64 KB
  unsigned short* Bp2 = Bp1 + 32768;                     // 32 KB

  pack_w_kernel<<<192, 256, 0, stream>>>(W1, W2, Bp1, Bp2);
  edge_fused_nt<<<ntiles, 256, 0, stream>>>(x, ea, eidx, W1, b1, b2, Bp1, Bp2, outp, E);
}

// Round 21
// 131.342 us; speedup vs baseline: 3.6200x; 1.1527x over previous
//
#include <hip/hip_runtime.h>
#include <hip/hip_bf16.h>

typedef __attribute__((ext_vector_type(4))) float f32x4;
typedef __attribute__((ext_vector_type(8))) short bf16x8;

__device__ __forceinline__ unsigned short f2bf(float f) {
  union { float f; unsigned int u; } v; v.f = f;
  unsigned int u = v.u;
  unsigned int r = (u + 0x7FFFu + ((u >> 16) & 1u)) >> 16;  // RNE
  return (unsigned short)r;
}

// ---------------- prep: pack W1(rows 4..260) and W2 into MFMA-B fragment order ----
__global__ void pack_w_kernel(const float* __restrict__ W1, const float* __restrict__ W2,
                              unsigned short* __restrict__ Bp1, unsigned short* __restrict__ Bp2) {
  int p = blockIdx.x * 256 + threadIdx.x;
  if (p < 32768) {                      // 256x128 for layer 1 (W1 rows 4..260)
    int j = p & 7, n = (p >> 3) & 127, kb = p >> 10;
    Bp1[p] = f2bf(W1[(4 + kb * 8 + j) * 128 + n]);
  } else if (p < 49152) {               // 128x128 for layer 2
    int q = p - 32768;
    int j = q & 7, n = (q >> 3) & 127, kb = q >> 10;
    Bp2[q] = f2bf(W2[(kb * 8 + j) * 128 + n]);
  }
}

// ---------------- prep: x fp32 -> bf16 ----------------
__global__ void convert_x_kernel(const float* __restrict__ x, unsigned short* __restrict__ xb, int n8) {
  int i = blockIdx.x * blockDim.x + threadIdx.x;
  if (i >= n8) return;
  const float4* s = (const float4*)x + (size_t)i * 2;
  float4 a = s[0], b = s[1];
  unsigned short h[8] = {f2bf(a.x), f2bf(a.y), f2bf(a.z), f2bf(a.w),
                         f2bf(b.x), f2bf(b.y), f2bf(b.z), f2bf(b.w)};
  int4 pk; __builtin_memcpy(&pk, h, 16);
  ((int4*)xb)[i] = pk;
}

constexpr int BM = 64;

// ---------------- main fused kernel: one 64-edge tile per block, 3 blocks/CU ----
// R16 VERBATIM — the measured optimum (131.8 us) across R1-R20:
// - 10000 blocks x 256 threads, one 64-edge tile each, 3 blocks/CU (49 KB LDS).
//   This is the ONLY clean-traffic configuration: 4/CU, 2-tile blocks, 8-wave
//   blocks, and persistent grids all amplify WRITE 2-4x (R5/R6/R7/R14/R17/R18/R19).
// - Staged normal-load bf16 gather (separate convert_x pass; fused fp32 gather
//   re-pays the savings in gather bytes, R9/R20).
// - Hoisted B-fragments above the gather barrier (R2's latency win).
// - NT full-line epilogue via padded LDS restage: 64 lanes x 16 B contiguous per
//   wave-instruction -> write-combines to HBM, no L2 dirty lines (R16's -16%).
//   (Partial-line NT is catastrophic: R3.)
__global__ __launch_bounds__(256, 3)
void edge_nt(const unsigned short* __restrict__ xb,
             const float* __restrict__ ea, const int* __restrict__ eidx,
             const float* __restrict__ W1, const float* __restrict__ b1,
             const float* __restrict__ b2,
             const unsigned short* __restrict__ Bp1, const unsigned short* __restrict__ Bp2,
             float* __restrict__ outp, int E) {
  __shared__ int4 AldsV[2112];   // 33 KB: A-tile [64][256] bf16 swizzled; reused as f32 out-stage [64][132]
  __shared__ int4 HldsV[1024];   // 16 KB  h [64][128] bf16, XOR-swizzled
  __shared__ float ealds[256];   // 64 edges x 4 attrs

  char* Alds = (char*)AldsV;
  float* Olds = (float*)AldsV;   // overlay (valid after the pre-layer-2 barrier)
  char* Hlds = (char*)HldsV;

  const int tid  = threadIdx.x;
  const int lane = tid & 63;
  const int wq   = lane >> 4;
  const int l16  = lane & 15;
  const int wave = tid >> 6;
  const int g    = tid & 15;
  const int s0   = tid >> 4;
  const int eb   = blockIdx.x * BM;

  // ---- issue independent loads first: edge_attr, eidx ----
  ealds[tid] = ea[eb * 4 + tid];

  int idxv[8];
  #pragma unroll
  for (int it = 0; it < 8; ++it) {
    int seg = it * 16 + s0;
    idxv[it] = eidx[(seg & 1) * E + eb + (seg >> 1)];
  }

  // ---- gather loads: normal (L2-allocating) int4 loads into VGPRs ----
  int4 gv[8];
  #pragma unroll
  for (int it = 0; it < 8; ++it)
    gv[it] = *(const int4*)(xb + (size_t)idxv[it] * 128 + g * 8);

  const int c0 = wave * 32 + l16;
  const int c1 = c0 + 16;

  // ---- hoisted scalars + layer-1 B fragments (latency overlaps gather) ----
  const float bias0 = b1[c0], bias1 = b1[c1];
  const float w00 = W1[c0],       w01 = W1[128 + c0], w02 = W1[256 + c0], w03 = W1[384 + c0];
  const float w10 = W1[c1],       w11 = W1[128 + c1], w12 = W1[256 + c1], w13 = W1[384 + c1];
  const float bias20 = b2[c0], bias21 = b2[c1];

  bf16x8 bf1r[8][2];
  #pragma unroll
  for (int ks = 0; ks < 8; ++ks) {
    int kb = ks * 4 + wq;
    bf1r[ks][0] = __builtin_bit_cast(bf16x8, *(const int4*)(Bp1 + ((size_t)kb * 128 + c0) * 8));
    bf1r[ks][1] = __builtin_bit_cast(bf16x8, *(const int4*)(Bp1 + ((size_t)kb * 128 + c1) * 8));
  }

  // ---- stage gather into LDS (XOR-swizzled dest, b128 writes) ----
  #pragma unroll
  for (int it = 0; it < 8; ++it) {
    int seg = it * 16 + s0;
    int r = seg >> 1, half = seg & 1;
    int lofs = (r * 512 + half * 256 + g * 16) ^ ((r & 7) << 4);
    *(int4*)(Alds + lofs) = gv[it];
  }
  __syncthreads();

  // ---- layer 1 accumulator init: b1 + edge_attr x W1[0:4] in fp32 ----
  f32x4 acc[4][2];
  #pragma unroll
  for (int mf = 0; mf < 4; ++mf)
    #pragma unroll
    for (int rg = 0; rg < 4; ++rg) {
      int r = mf * 16 + wq * 4 + rg;
      float e0 = ealds[r * 4 + 0], e1 = ealds[r * 4 + 1];
      float e2 = ealds[r * 4 + 2], e3 = ealds[r * 4 + 3];
      acc[mf][0][rg] = bias0 + e0 * w00 + e1 * w01 + e2 * w02 + e3 * w03;
      acc[mf][1][rg] = bias1 + e0 * w10 + e1 * w11 + e2 * w12 + e3 * w13;
    }

  // ---- layer 1 MFMA: K = 256 (sender 128 | receiver 128), B from registers ----
  #pragma unroll
  for (int ks = 0; ks < 8; ++ks) {
    #pragma unroll
    for (int mf = 0; mf < 4; ++mf) {
      int r = mf * 16 + l16;
      int lofs = (r * 512 + ks * 64 + wq * 16) ^ ((r & 7) << 4);
      bf16x8 av = __builtin_bit_cast(bf16x8, *(const int4*)(Alds + lofs));
      acc[mf][0] = __builtin_amdgcn_mfma_f32_16x16x32_bf16(av, bf1r[ks][0], acc[mf][0], 0, 0, 0);
      acc[mf][1] = __builtin_amdgcn_mfma_f32_16x16x32_bf16(av, bf1r[ks][1], acc[mf][1], 0, 0, 0);
    }
  }

  // ---- layer-2 B fragments: issue now, latency hides under H-write + barrier ----
  bf16x8 bf2r[4][2];
  #pragma unroll
  for (int ks = 0; ks < 4; ++ks) {
    int kb = ks * 4 + wq;
    bf2r[ks][0] = __builtin_bit_cast(bf16x8, *(const int4*)(Bp2 + ((size_t)kb * 128 + c0) * 8));
    bf2r[ks][1] = __builtin_bit_cast(bf16x8, *(const int4*)(Bp2 + ((size_t)kb * 128 + c1) * 8));
  }

  // ---- ReLU + h -> LDS (bf16, swizzled) ----
  #pragma unroll
  for (int mf = 0; mf < 4; ++mf)
    #pragma unroll
    for (int nf = 0; nf < 2; ++nf) {
      int c = wave * 32 + nf * 16 + l16;
      #pragma unroll
      for (int rg = 0; rg < 4; ++rg) {
        int r = mf * 16 + wq * 4 + rg;
        float v = fmaxf(acc[mf][nf][rg], 0.0f);
        int lofs = (r * 256 + c * 2) ^ ((r & 7) << 4);
        *(unsigned short*)(Hlds + lofs) = f2bf(v);
      }
    }
  __syncthreads();   // after this barrier ALL waves are done reading Alds -> Olds overlay safe

  // ---- layer 2: K = 128 ----
  f32x4 acc2[4][2];
  #pragma unroll
  for (int mf = 0; mf < 4; ++mf) {
    acc2[mf][0] = (f32x4){bias20, bias20, bias20, bias20};
    acc2[mf][1] = (f32x4){bias21, bias21, bias21, bias21};
  }
  #pragma unroll
  for (int ks = 0; ks < 4; ++ks) {
    #pragma unroll
    for (int mf = 0; mf < 4; ++mf) {
      int r = mf * 16 + l16;
      int lofs = (r * 256 + ks * 64 + wq * 16) ^ ((r & 7) << 4);
      bf16x8 av = __builtin_bit_cast(bf16x8, *(const int4*)(Hlds + lofs));
      acc2[mf][0] = __builtin_amdgcn_mfma_f32_16x16x32_bf16(av, bf2r[ks][0], acc2[mf][0], 0, 0, 0);
      acc2[mf][1] = __builtin_amdgcn_mfma_f32_16x16x32_bf16(av, bf2r[ks][1], acc2[mf][1], 0, 0, 0);
    }
  }

  // ---- stage acc2 -> LDS f32 [64][132] (padded stride kills write conflicts) ----
  #pragma unroll
  for (int mf = 0; mf < 4; ++mf)
    #pragma unroll
    for (int nf = 0; nf < 2; ++nf) {
      int c = wave * 32 + nf * 16 + l16;
      #pragma unroll
      for (int rg = 0; rg < 4; ++rg) {
        int r = mf * 16 + wq * 4 + rg;
        Olds[r * 132 + c] = acc2[mf][nf][rg];
      }
    }
  __syncthreads();

  // ---- epilogue: contiguous NT full-line stores (1024 B per wave-instruction) ----
  float* outbase = outp + (size_t)eb * 128;
  #pragma unroll
  for (int p = 0; p < 8; ++p) {
    int i = p * 256 + tid;            // float4 index within the 64x128 tile
    int r = i >> 5, c4 = i & 31;      // 32 float4 per row
    f32x4 v = *(const f32x4*)(Olds + r * 132 + c4 * 4);
    __builtin_nontemporal_store(v, (f32x4*)(outbase + i * 4));
  }
}

// ---------------- fallback (fp32 gather, fused, 3/CU) for small ws ----------------
__global__ __launch_bounds__(256, 3)
void edge_fused_f32(const float* __restrict__ xf,
                    const float* __restrict__ ea, const int* __restrict__ eidx,
                    const float* __restrict__ W1, const float* __restrict__ b1,
                    const float* __restrict__ b2,
                    const unsigned short* __restrict__ Bp1, const unsigned short* __restrict__ Bp2,
                    float* __restrict__ outp, int E) {
  __shared__ int4 AldsV[2048];
  __shared__ int4 HldsV[1024];
  __shared__ float ealds[256];
  char* Alds = (char*)AldsV;
  char* Hlds = (char*)HldsV;

  const int tid  = threadIdx.x;
  const int lane = tid & 63;
  const int wq   = lane >> 4;
  const int l16  = lane & 15;
  const int wave = tid >> 6;
  const int g    = tid & 15;
  const int s0   = tid >> 4;
  const int eb   = blockIdx.x * BM;

  ealds[tid] = ea[eb * 4 + tid];

  int idxv[8];
  #pragma unroll
  for (int it = 0; it < 8; ++it) {
    int seg = it * 16 + s0;
    idxv[it] = eidx[(seg & 1) * E + eb + (seg >> 1)];
  }

  float4 ga[8], gb[8];
  #pragma unroll
  for (int it = 0; it < 8; ++it) {
    const float* src = xf + (size_t)idxv[it] * 128 + g * 8;
    ga[it] = *(const float4*)src;
    gb[it] = *(const float4*)(src + 4);
  }

  const int c0 = wave * 32 + l16;
  const int c1 = c0 + 16;
  const float bias0 = b1[c0], bias1 = b1[c1];
  const float w00 = W1[c0],       w01 = W1[128 + c0], w02 = W1[256 + c0], w03 = W1[384 + c0];
  const float w10 = W1[c1],       w11 = W1[128 + c1], w12 = W1[256 + c1], w13 = W1[384 + c1];
  const float bias20 = b2[c0], bias21 = b2[c1];

  bf16x8 bf1r[8][2];
  #pragma unroll
  for (int ks = 0; ks < 8; ++ks) {
    int kb = ks * 4 + wq;
    bf1r[ks][0] = __builtin_bit_cast(bf16x8, *(const int4*)(Bp1 + ((size_t)kb * 128 + c0) * 8));
    bf1r[ks][1] = __builtin_bit_cast(bf16x8, *(const int4*)(Bp1 + ((size_t)kb * 128 + c1) * 8));
  }

  #pragma unroll
  for (int it = 0; it < 8; ++it) {
    int seg = it * 16 + s0;
    int r = seg >> 1, half = seg & 1;
    int lofs = (r * 512 + half * 256 + g * 16) ^ ((r & 7) << 4);
    unsigned short h[8] = {f2bf(ga[it].x), f2bf(ga[it].y), f2bf(ga[it].z), f2bf(ga[it].w),
                           f2bf(gb[it].x), f2bf(gb[it].y), f2bf(gb[it].z), f2bf(gb[it].w)};
    int4 pk; __builtin_memcpy(&pk, h, 16);
    *(int4*)(Alds + lofs) = pk;
  }
  __syncthreads();

  f32x4 acc[4][2];
  #pragma unroll
  for (int mf = 0; mf < 4; ++mf)
    #pragma unroll
    for (int rg = 0; rg < 4; ++rg) {
      int r = mf * 16 + wq * 4 + rg;
      float e0 = ealds[r * 4 + 0], e1 = ealds[r * 4 + 1];
      float e2 = ealds[r * 4 + 2], e3 = ealds[r * 4 + 3];
      acc[mf][0][rg] = bias0 + e0 * w00 + e1 * w01 + e2 * w02 + e3 * w03;
      acc[mf][1][rg] = bias1 + e0 * w10 + e1 * w11 + e2 * w12 + e3 * w13;
    }

  #pragma unroll
  for (int ks = 0; ks < 8; ++ks)
    #pragma unroll
    for (int mf = 0; mf < 4; ++mf) {
      int r = mf * 16 + l16;
      int lofs = (r * 512 + ks * 64 + wq * 16) ^ ((r & 7) << 4);
      bf16x8 av = __builtin_bit_cast(bf16x8, *(const int4*)(Alds + lofs));
      acc[mf][0] = __builtin_amdgcn_mfma_f32_16x16x32_bf16(av, bf1r[ks][0], acc[mf][0], 0, 0, 0);
      acc[mf][1] = __builtin_amdgcn_mfma_f32_16x16x32_bf16(av, bf1r[ks][1], acc[mf][1], 0, 0, 0);
    }

  bf16x8 bf2r[4][2];
  #pragma unroll
  for (int ks = 0; ks < 4; ++ks) {
    int kb = ks * 4 + wq;
    bf2r[ks][0] = __builtin_bit_cast(bf16x8, *(const int4*)(Bp2 + ((size_t)kb * 128 + c0) * 8));
    bf2r[ks][1] = __builtin_bit_cast(bf16x8, *(const int4*)(Bp2 + ((size_t)kb * 128 + c1) * 8));
  }

  #pragma unroll
  for (int mf = 0; mf < 4; ++mf)
    #pragma unroll
    for (int nf = 0; nf < 2; ++nf) {
      int c = wave * 32 + nf * 16 + l16;
      #pragma unroll
      for (int rg = 0; rg < 4; ++rg) {
        int r = mf * 16 + wq * 4 + rg;
        float v = fmaxf(acc[mf][nf][rg], 0.0f);
        int lofs = (r * 256 + c * 2) ^ ((r & 7) << 4);
        *(unsigned short*)(Hlds + lofs) = f2bf(v);
      }
    }
  __syncthreads();

  f32x4 acc2[4][2];
  #pragma unroll
  for (int mf = 0; mf < 4; ++mf) {
    acc2[mf][0] = (f32x4){bias20, bias20, bias20, bias20};
    acc2[mf][1] = (f32x4){bias21, bias21, bias21, bias21};
  }
  #pragma unroll
  for (int ks = 0; ks < 4; ++ks)
    #pragma unroll
    for (int mf = 0; mf < 4; ++mf) {
      int r = mf * 16 + l16;
      int lofs = (r * 256 + ks * 64 + wq * 16) ^ ((r & 7) << 4);
      bf16x8 av = __builtin_bit_cast(bf16x8, *(const int4*)(Hlds + lofs));
      acc2[mf][0] = __builtin_amdgcn_mfma_f32_16x16x32_bf16(av, bf2r[ks][0], acc2[mf][0], 0, 0, 0);
      acc2[mf][1] = __builtin_amdgcn_mfma_f32_16x16x32_bf16(av, bf2r[ks][1], acc2[mf][1], 0, 0, 0);
    }

  #pragma unroll
  for (int mf = 0; mf < 4; ++mf)
    #pragma unroll
    for (int nf = 0; nf < 2; ++nf) {
      int c = wave * 32 + nf * 16 + l16;
      #pragma unroll
      for (int rg = 0; rg < 4; ++rg) {
        int r = mf * 16 + wq * 4 + rg;
        outp[(size_t)(eb + r) * 128 + c] = acc2[mf][nf][rg];
      }
    }
}

extern "C" void kernel_launch(void* const* d_in, const int* in_sizes, int n_in,
                              void* d_out, int out_size, void* d_ws, size_t ws_size,
                              hipStream_t stream) {
  const float* x  = (const float*)d_in[0];
  const float* ea = (const float*)d_in[1];
  const int* eidx = (const int*)d_in[2];
  const float* W1 = (const float*)d_in[3];
  const float* b1 = (const float*)d_in[4];
  const float* W2 = (const float*)d_in[5];
  const float* b2 = (const float*)d_in[6];
  float* outp = (float*)d_out;

  const int E = in_sizes[2] / 2;
  const int nnodes = in_sizes[0] / 128;
  const int ntiles = E / BM;

  unsigned short* Bp1 = (unsigned short*)d_ws;           // 64 KB
  unsigned short* Bp2 = Bp1 + 32768;                     // 32 KB
  unsigned short* xb  = (unsigned short*)((char*)d_ws + 98304);
  const size_t need = 98304 + (size_t)nnodes * 128 * 2;

  pack_w_kernel<<<192, 256, 0, stream>>>(W1, W2, Bp1, Bp2);

  if (ws_size >= need) {
    int n8 = nnodes * 128 / 8;
    convert_x_kernel<<<(n8 + 255) / 256, 256, 0, stream>>>(x, xb, n8);
    edge_nt<<<ntiles, 256, 0, stream>>>(xb, ea, eidx, W1, b1, b2, Bp1, Bp2, outp, E);
  } else {
    edge_fused_f32<<<ntiles, 256, 0, stream>>>(x, ea, eidx, W1, b1, b2, Bp1, Bp2, outp, E);
  }
}